// Round 1
// baseline (269.793 us; speedup 1.0000x reference)
//
#include <hip/hip_runtime.h>
#include <hip/hip_bf16.h>

typedef __bf16 bf16_t;
typedef __bf16 bf16x8 __attribute__((ext_vector_type(8)));
typedef float  f32x4  __attribute__((ext_vector_type(4)));

#define B_ 8
#define T_ 2048
#define C_ 1024
#define H_ 64

#define MFMA16(a, b, c) __builtin_amdgcn_mfma_f32_16x16x32_bf16((a), (b), (c), 0, 0, 0)

// (b, tile16, kstep64) work units: per b = sum_{m=0}^{127}(m/4+1) = 2112
#define UNITS_PER_B 2112
#define UNITS_TOTAL (8 * UNITS_PER_B)   // 16896
#define N_WAVES 8192                     // 2048 blocks x 4 waves, ~2.06 units/wave

// ---------------------------------------------------------------------------
// Kernel 1: W fp32 -> concatenated hi/lo bf16 [192][1024] (q|k|v rows).
// ---------------------------------------------------------------------------
__global__ __launch_bounds__(256) void wconv_kernel(
    const float* __restrict__ Wk, const float* __restrict__ Wq,
    const float* __restrict__ Wv,
    bf16_t* __restrict__ Wh, bf16_t* __restrict__ Wl)
{
    int i = blockIdx.x * 256 + threadIdx.x;
    int r = i >> 10;
    int c = i & 1023;
    float v;
    if (r < 64)       v = Wq[r * 1024 + c];
    else if (r < 128) v = Wk[(r - 64) * 1024 + c];
    else              v = Wv[(r - 128) * 1024 + c];
    bf16_t h = (bf16_t)v;
    Wh[i] = h;
    Wl[i] = (bf16_t)(v - (float)h);
}

// ---------------------------------------------------------------------------
// Kernel 2: zero Oacc (4 MB) + lacc (64 KB), contiguous. 266240 f32x4.
// ---------------------------------------------------------------------------
__global__ __launch_bounds__(256) void zero_kernel(f32x4* __restrict__ p)
{
    int i = blockIdx.x * 256 + threadIdx.x;
    if (i < 266240) p[i] = (f32x4){0.f, 0.f, 0.f, 0.f};
}

// ---------------------------------------------------------------------------
// Kernel 3: QKV projection.  512 blocks x 32 rows -> 2 blocks/CU so barrier
// drains in one block overlap with compute in the other.  Each wave: 16 rows
// (mhalf) x 96 cols (nhalf), acc[6].  Double-buffered LDS, 1 barrier/iter.
// ---------------------------------------------------------------------------
__global__ __launch_bounds__(256, 2) void proj_kernel(
    const float*  __restrict__ x,
    const bf16_t* __restrict__ Wh, const bf16_t* __restrict__ Wl,
    bf16_t* __restrict__ qh, bf16_t* __restrict__ ql,
    bf16_t* __restrict__ kh, bf16_t* __restrict__ kl,
    bf16_t* __restrict__ vh)
{
    // [dbuf][hi/lo][192 rows x 40 cols] bf16: 61440 B -> 2 blocks/CU (122 KB)
    __shared__ bf16_t Ws[2][2][192 * 40];

    const int tid   = threadIdx.x;
    const int wid   = tid >> 6;
    const int lane  = tid & 63;
    const int quad  = lane >> 4;
    const int l16   = lane & 15;
    const int mhalf = wid >> 1;            // which 16-row group
    const int nhalf = wid & 1;             // which 96-col group
    const int g     = blockIdx.x * 32 + mhalf * 16 + l16;
    const float* xrow = x + (size_t)g * C_;

    bf16x8 wreg[6];
    auto loadW = [&](int k0) {
        #pragma unroll
        for (int it = 0; it < 6; ++it) {
            int c   = tid + it * 256;
            int mat = (c >= 768);
            int cc  = c - (mat ? 768 : 0);
            int row = cc >> 2, prt = cc & 3;
            wreg[it] = *(const bf16x8*)((mat ? Wl : Wh) + row * 1024 + k0 + prt * 8);
        }
    };
    auto storeW = [&](int buf) {
        #pragma unroll
        for (int it = 0; it < 6; ++it) {
            int c   = tid + it * 256;
            int mat = (c >= 768);
            int cc  = c - (mat ? 768 : 0);
            int row = cc >> 2, prt = cc & 3;
            *(bf16x8*)(&Ws[buf][mat][row * 40 + prt * 8]) = wreg[it];
        }
    };

    f32x4 x0a, x0b, x1a, x1b;
    loadW(0);
    storeW(0);
    x0a = *(const f32x4*)(xrow + quad * 8);
    x0b = *(const f32x4*)(xrow + quad * 8 + 4);
    x1a = *(const f32x4*)(xrow + 32 + quad * 8);
    x1b = *(const f32x4*)(xrow + 32 + quad * 8 + 4);

    f32x4 acc[6];
    for (int i = 0; i < 6; ++i) acc[i] = (f32x4){0.f, 0.f, 0.f, 0.f};
    __syncthreads();

    for (int it = 0; it < 32; ++it) {
        const int buf = it & 1;
        if (it + 1 < 32) loadW((it + 1) * 32);

        float xv[8];
        *(f32x4*)xv       = x0a;
        *(f32x4*)(xv + 4) = x0b;
        bf16x8 ah, al;
        #pragma unroll
        for (int jj = 0; jj < 8; ++jj) {
            bf16_t h = (bf16_t)xv[jj];
            ah[jj] = h;
            al[jj] = (bf16_t)(xv[jj] - (float)h);
        }
        x0a = x1a; x0b = x1b;
        if (it + 2 < 32) {
            x1a = *(const f32x4*)(xrow + (it + 2) * 32 + quad * 8);
            x1b = *(const f32x4*)(xrow + (it + 2) * 32 + quad * 8 + 4);
        }

        #pragma unroll
        for (int nt = 0; nt < 6; ++nt) {
            int nrow = (nhalf * 6 + nt) * 16 + l16;
            bf16x8 bh = *(const bf16x8*)(&Ws[buf][0][nrow * 40 + quad * 8]);
            bf16x8 bl = *(const bf16x8*)(&Ws[buf][1][nrow * 40 + quad * 8]);
            acc[nt] = MFMA16(ah, bh, acc[nt]);
            acc[nt] = MFMA16(ah, bl, acc[nt]);
            acc[nt] = MFMA16(al, bh, acc[nt]);
        }

        if (it + 1 < 32) storeW(buf ^ 1);
        __syncthreads();
    }

    // epilogue: D layout col=lane&15, row=quad*4+reg
    const int rowbase = blockIdx.x * 32 + mhalf * 16 + quad * 4;
    for (int nt = 0; nt < 6; ++nt) {
        int n = (nhalf * 6 + nt) * 16 + l16;
        for (int rr = 0; rr < 4; ++rr) {
            int grow = rowbase + rr;
            int bb = grow >> 11, t = grow & 2047;
            float v  = acc[nt][rr];
            bf16_t h = (bf16_t)v;
            if (n < 64) {
                int off = (bb * T_ + t) * H_ + n;
                qh[off] = h; ql[off] = (bf16_t)(v - (float)h);
            } else if (n < 128) {
                int off = (bb * T_ + t) * H_ + (n - 64);
                kh[off] = h; kl[off] = (bf16_t)(v - (float)h);
            } else {
                vh[(bb * H_ + (n - 128)) * T_ + t] = h;
            }
        }
    }
}

// ---------------------------------------------------------------------------
// Kernel 4: attention.  8192 waves walk ~2 units each; no barriers; fixed-max
// softmax (p=exp(s/8-20)) makes partials purely additive (atomicAdd combine).
// XCD swizzle: each XCD gets a contiguous unit range -> K/V slice L2-resident.
// Occupancy: VGPR=56 (<=64) and LDS 18432*8=147456 (<=160K) both fit 8
// blocks/CU -> __launch_bounds__(256,8) makes all 2048 blocks (=8x256CU)
// co-resident in ONE round with 8 waves/SIMD latency hiding (was 4, 2 rounds).
// ---------------------------------------------------------------------------
__global__ __launch_bounds__(256, 8) void attn_kernel(
    const bf16_t* __restrict__ qh, const bf16_t* __restrict__ ql,
    const bf16_t* __restrict__ kh, const bf16_t* __restrict__ kl,
    const bf16_t* __restrict__ vh,
    float* __restrict__ Oacc, float* __restrict__ lacc)
{
    __shared__ bf16_t Plds[4][2][16 * 72];   // per-wave double-buffered P

    const int tid  = threadIdx.x;
    const int wid  = tid >> 6;
    const int lane = tid & 63;
    const int quad = lane >> 4;
    const int l16  = lane & 15;
    // XCD swizzle: XCD x (bid%8) owns contiguous gw range -> contiguous units
    const int bidx = (blockIdx.x & 7) * 256 + (blockIdx.x >> 3);
    const int gw   = bidx * 4 + wid;                  // 0..8191

    const int U0  = (int)(((long long)gw * UNITS_TOTAL) >> 13);
    const int U1  = (int)(((long long)(gw + 1) * UNITS_TOTAL) >> 13);
    const int cnt = U1 - U0;

    // decode U0 -> (b, a, r, j):  rem = 2a(a+1) + r(a+1) + j
    int b   = U0 / UNITS_PER_B;
    int rem = U0 - b * UNITS_PER_B;
    int a   = (int)((sqrtf((float)(2 * rem) + 1.0f) - 1.0f) * 0.5f);
    while (2 * (a + 1) * (a + 2) <= rem) ++a;
    while (2 * a * (a + 1) > rem) --a;
    int rem2 = rem - 2 * a * (a + 1);
    int r = 0;
    while (rem2 >= (a + 1)) { rem2 -= (a + 1); ++r; }
    int j = rem2;
    int m = 4 * a + r;

    f32x4  O[4];
    float  rowsum[4];
    bf16x8 aqh[2], aql[2];
    bool   needQ = true;
    int    pb = 0;

    auto flush = [&]() {
        #pragma unroll
        for (int rr = 0; rr < 4; ++rr) {
            int trow = b * T_ + 16 * m + quad * 4 + rr;
            #pragma unroll
            for (int ht = 0; ht < 4; ++ht)
                atomicAdd(Oacc + trow * H_ + ht * 16 + l16, O[ht][rr]);
            // pre-reduce rowsum across the 16 l16 lanes, one atomic per row
            float s_ = rowsum[rr];
            s_ += __shfl_xor(s_, 1, 64);
            s_ += __shfl_xor(s_, 2, 64);
            s_ += __shfl_xor(s_, 4, 64);
            s_ += __shfl_xor(s_, 8, 64);
            if (l16 == 0) atomicAdd(lacc + trow, s_);
        }
    };

    for (int c = 0; c < cnt; ++c) {
        if (needQ) {
            int qoff = (b * T_ + 16 * m + l16) * H_;
            #pragma unroll
            for (int kk = 0; kk < 2; ++kk) {
                aqh[kk] = *(const bf16x8*)(qh + qoff + kk * 32 + quad * 8);
                aql[kk] = *(const bf16x8*)(ql + qoff + kk * 32 + quad * 8);
            }
            for (int i = 0; i < 4; ++i) { O[i] = (f32x4){0.f,0.f,0.f,0.f}; rowsum[i] = 0.f; }
            needQ = false;
        }

        const int  s0   = 64 * j;
        const bool diag = (j == a);

        // ---- S = q k^T (3-term hi/lo)
        f32x4 S[4];
        for (int i = 0; i < 4; ++i) S[i] = (f32x4){0.f,0.f,0.f,0.f};
        const bf16_t* kb = kh + (b * T_ + s0) * H_;
        const bf16_t* lb = kl + (b * T_ + s0) * H_;
        #pragma unroll
        for (int nt = 0; nt < 4; ++nt) {
            int ro = (nt * 16 + l16) * H_;
            #pragma unroll
            for (int kk = 0; kk < 2; ++kk) {
                bf16x8 bh = *(const bf16x8*)(kb + ro + kk * 32 + quad * 8);
                bf16x8 bl = *(const bf16x8*)(lb + ro + kk * 32 + quad * 8);
                S[nt] = MFMA16(aqh[kk], bh, S[nt]);
                S[nt] = MFMA16(aqh[kk], bl, S[nt]);
                S[nt] = MFMA16(aql[kk], bh, S[nt]);
            }
        }

        // ---- fixed-max softmax: p = exp(s/8 - 20); no reductions, no rescale
        bf16_t* Pw = Plds[wid][pb];
        const int rowb = 16 * m + quad * 4;
        #pragma unroll
        for (int nt = 0; nt < 4; ++nt) {
            int colt = s0 + nt * 16 + l16;
            #pragma unroll
            for (int rr = 0; rr < 4; ++rr) {
                float p = __expf(fmaf(S[nt][rr], 0.125f, -20.0f));
                if (diag && colt > rowb + rr) p = 0.f;
                rowsum[rr] += p;
                Pw[(quad * 4 + rr) * 72 + nt * 16 + l16] = (bf16_t)p;
            }
        }
        pb ^= 1;

        // ---- P: LDS round-trip D-layout -> A-layout (same wave, HW-ordered)
        bf16x8 ap[2];
        #pragma unroll
        for (int kk = 0; kk < 2; ++kk)
            ap[kk] = *(const bf16x8*)(Pw + l16 * 72 + kk * 32 + quad * 8);

        // ---- O += P * Vh (V transposed (H,T))
        const bf16_t* vb = vh + b * H_ * T_ + s0;
        #pragma unroll
        for (int ht = 0; ht < 4; ++ht) {
            int vo = (ht * 16 + l16) * T_;
            #pragma unroll
            for (int kk = 0; kk < 2; ++kk) {
                bf16x8 bv = *(const bf16x8*)(vb + vo + kk * 32 + quad * 8);
                O[ht] = MFMA16(ap[kk], bv, O[ht]);
            }
        }

        // ---- advance walk
        ++j;
        if (j == a + 1) {
            flush();
            j = 0; needQ = true;
            ++r;
            if (r == 4) { r = 0; ++a; if (a == 32) { a = 0; ++b; } }
            m = 4 * a + r;
        }
    }
    if (!needQ) flush();
}

// ---------------------------------------------------------------------------
// Kernel 5: out = Oacc / lacc
// ---------------------------------------------------------------------------
__global__ __launch_bounds__(256) void div_kernel(
    const float* __restrict__ Oacc, const float* __restrict__ lacc,
    float* __restrict__ out)
{
    int i = blockIdx.x * 256 + threadIdx.x;          // f32x4 index, 262144 total
    f32x4 o   = ((const f32x4*)Oacc)[i];
    float inv = 1.0f / lacc[i >> 4];
    ((f32x4*)out)[i] = o * inv;
}

// ---------------------------------------------------------------------------
extern "C" void kernel_launch(void* const* d_in, const int* in_sizes, int n_in,
                              void* d_out, int out_size, void* d_ws, size_t ws_size,
                              hipStream_t stream)
{
    const float* x  = (const float*)d_in[0];
    const float* Wk = (const float*)d_in[1];
    const float* Wq = (const float*)d_in[2];
    const float* Wv = (const float*)d_in[3];
    float* out = (float*)d_out;

    char* ws = (char*)d_ws;
    const size_t WSZ = 192 * 1024 * sizeof(bf16_t);            // 393216
    const size_t QSZ = (size_t)B_ * T_ * H_ * sizeof(bf16_t);  // 2097152
    bf16_t* Wh   = (bf16_t*)(ws);
    bf16_t* Wl   = (bf16_t*)(ws + WSZ);
    bf16_t* qh   = (bf16_t*)(ws + 2 * WSZ);
    bf16_t* ql   = (bf16_t*)(ws + 2 * WSZ + 1 * QSZ);
    bf16_t* kh   = (bf16_t*)(ws + 2 * WSZ + 2 * QSZ);
    bf16_t* kl   = (bf16_t*)(ws + 2 * WSZ + 3 * QSZ);
    bf16_t* vh   = (bf16_t*)(ws + 2 * WSZ + 4 * QSZ);
    float*  Oacc = (float*)(ws + 2 * WSZ + 5 * QSZ);           // 4 MB
    float*  lacc = (float*)(ws + 2 * WSZ + 5 * QSZ + (size_t)B_ * T_ * H_ * 4);

    hipLaunchKernelGGL(zero_kernel, dim3(1040), dim3(256), 0, stream, (f32x4*)Oacc);
    hipLaunchKernelGGL(wconv_kernel, dim3(768), dim3(256), 0, stream, Wk, Wq, Wv, Wh, Wl);
    hipLaunchKernelGGL(proj_kernel, dim3(512), dim3(256), 0, stream,
                       x, Wh, Wl, qh, ql, kh, kl, vh);
    hipLaunchKernelGGL(attn_kernel, dim3(2048), dim3(256), 0, stream,
                       qh, ql, kh, kl, vh, Oacc, lacc);
    hipLaunchKernelGGL(div_kernel, dim3(1024), dim3(256), 0, stream, Oacc, lacc, out);
}

// Round 2
// 212.899 us; speedup vs baseline: 1.2672x; 1.2672x over previous
//
#include <hip/hip_runtime.h>
#include <hip/hip_bf16.h>

typedef __bf16 bf16_t;
typedef __bf16 bf16x8 __attribute__((ext_vector_type(8)));
typedef float  f32x4  __attribute__((ext_vector_type(4)));

#define B_ 8
#define T_ 2048
#define C_ 1024
#define H_ 64

#define MFMA16(a, b, c) __builtin_amdgcn_mfma_f32_16x16x32_bf16((a), (b), (c), 0, 0, 0)

// (b, tile16, kstep64) work units: per b = sum_{m=0}^{127}(m/4+1) = 2112
#define UNITS_PER_B 2112
#define UNITS_TOTAL (8 * UNITS_PER_B)   // 16896
#define N_WAVES 8192                     // 2048 blocks x 4 waves, ~2.06 units/wave

// ---------------------------------------------------------------------------
// Kernel 1: W fp32 -> concatenated hi/lo bf16 [192][1024] (q|k|v rows).
// ---------------------------------------------------------------------------
__global__ __launch_bounds__(256) void wconv_kernel(
    const float* __restrict__ Wk, const float* __restrict__ Wq,
    const float* __restrict__ Wv,
    bf16_t* __restrict__ Wh, bf16_t* __restrict__ Wl)
{
    int i = blockIdx.x * 256 + threadIdx.x;
    int r = i >> 10;
    int c = i & 1023;
    float v;
    if (r < 64)       v = Wq[r * 1024 + c];
    else if (r < 128) v = Wk[(r - 64) * 1024 + c];
    else              v = Wv[(r - 128) * 1024 + c];
    bf16_t h = (bf16_t)v;
    Wh[i] = h;
    Wl[i] = (bf16_t)(v - (float)h);
}

// ---------------------------------------------------------------------------
// Kernel 2: zero Oacc (4 MB) + lacc (64 KB), contiguous. 266240 f32x4.
// ---------------------------------------------------------------------------
__global__ __launch_bounds__(256) void zero_kernel(f32x4* __restrict__ p)
{
    int i = blockIdx.x * 256 + threadIdx.x;
    if (i < 266240) p[i] = (f32x4){0.f, 0.f, 0.f, 0.f};
}

// ---------------------------------------------------------------------------
// Kernel 3: QKV projection.  512 blocks x 32 rows -> 2 blocks/CU so barrier
// drains in one block overlap with compute in the other.  Each wave: 16 rows
// (mhalf) x 96 cols (nhalf), acc[6].  Double-buffered LDS, 1 barrier/iter.
// ---------------------------------------------------------------------------
__global__ __launch_bounds__(256, 2) void proj_kernel(
    const float*  __restrict__ x,
    const bf16_t* __restrict__ Wh, const bf16_t* __restrict__ Wl,
    bf16_t* __restrict__ qh, bf16_t* __restrict__ ql,
    bf16_t* __restrict__ kh, bf16_t* __restrict__ kl,
    bf16_t* __restrict__ vh)
{
    // [dbuf][hi/lo][192 rows x 40 cols] bf16: 61440 B -> 2 blocks/CU (122 KB)
    __shared__ bf16_t Ws[2][2][192 * 40];

    const int tid   = threadIdx.x;
    const int wid   = tid >> 6;
    const int lane  = tid & 63;
    const int quad  = lane >> 4;
    const int l16   = lane & 15;
    const int mhalf = wid >> 1;            // which 16-row group
    const int nhalf = wid & 1;             // which 96-col group
    const int g     = blockIdx.x * 32 + mhalf * 16 + l16;
    const float* xrow = x + (size_t)g * C_;

    bf16x8 wreg[6];
    auto loadW = [&](int k0) {
        #pragma unroll
        for (int it = 0; it < 6; ++it) {
            int c   = tid + it * 256;
            int mat = (c >= 768);
            int cc  = c - (mat ? 768 : 0);
            int row = cc >> 2, prt = cc & 3;
            wreg[it] = *(const bf16x8*)((mat ? Wl : Wh) + row * 1024 + k0 + prt * 8);
        }
    };
    auto storeW = [&](int buf) {
        #pragma unroll
        for (int it = 0; it < 6; ++it) {
            int c   = tid + it * 256;
            int mat = (c >= 768);
            int cc  = c - (mat ? 768 : 0);
            int row = cc >> 2, prt = cc & 3;
            *(bf16x8*)(&Ws[buf][mat][row * 40 + prt * 8]) = wreg[it];
        }
    };

    f32x4 x0a, x0b, x1a, x1b;
    loadW(0);
    storeW(0);
    x0a = *(const f32x4*)(xrow + quad * 8);
    x0b = *(const f32x4*)(xrow + quad * 8 + 4);
    x1a = *(const f32x4*)(xrow + 32 + quad * 8);
    x1b = *(const f32x4*)(xrow + 32 + quad * 8 + 4);

    f32x4 acc[6];
    for (int i = 0; i < 6; ++i) acc[i] = (f32x4){0.f, 0.f, 0.f, 0.f};
    __syncthreads();

    for (int it = 0; it < 32; ++it) {
        const int buf = it & 1;
        if (it + 1 < 32) loadW((it + 1) * 32);

        float xv[8];
        *(f32x4*)xv       = x0a;
        *(f32x4*)(xv + 4) = x0b;
        bf16x8 ah, al;
        #pragma unroll
        for (int jj = 0; jj < 8; ++jj) {
            bf16_t h = (bf16_t)xv[jj];
            ah[jj] = h;
            al[jj] = (bf16_t)(xv[jj] - (float)h);
        }
        x0a = x1a; x0b = x1b;
        if (it + 2 < 32) {
            x1a = *(const f32x4*)(xrow + (it + 2) * 32 + quad * 8);
            x1b = *(const f32x4*)(xrow + (it + 2) * 32 + quad * 8 + 4);
        }

        #pragma unroll
        for (int nt = 0; nt < 6; ++nt) {
            int nrow = (nhalf * 6 + nt) * 16 + l16;
            bf16x8 bh = *(const bf16x8*)(&Ws[buf][0][nrow * 40 + quad * 8]);
            bf16x8 bl = *(const bf16x8*)(&Ws[buf][1][nrow * 40 + quad * 8]);
            acc[nt] = MFMA16(ah, bh, acc[nt]);
            acc[nt] = MFMA16(ah, bl, acc[nt]);
            acc[nt] = MFMA16(al, bh, acc[nt]);
        }

        if (it + 1 < 32) storeW(buf ^ 1);
        __syncthreads();
    }

    // epilogue: D layout col=lane&15, row=quad*4+reg
    const int rowbase = blockIdx.x * 32 + mhalf * 16 + quad * 4;
    for (int nt = 0; nt < 6; ++nt) {
        int n = (nhalf * 6 + nt) * 16 + l16;
        for (int rr = 0; rr < 4; ++rr) {
            int grow = rowbase + rr;
            int bb = grow >> 11, t = grow & 2047;
            float v  = acc[nt][rr];
            bf16_t h = (bf16_t)v;
            if (n < 64) {
                int off = (bb * T_ + t) * H_ + n;
                qh[off] = h; ql[off] = (bf16_t)(v - (float)h);
            } else if (n < 128) {
                int off = (bb * T_ + t) * H_ + (n - 64);
                kh[off] = h; kl[off] = (bf16_t)(v - (float)h);
            } else {
                vh[(bb * H_ + (n - 128)) * T_ + t] = h;
            }
        }
    }
}

// ---------------------------------------------------------------------------
// Kernel 4: attention.  8192 waves walk ~2 units each; no barriers; fixed-max
// softmax (p=exp(s/8-20)) makes partials purely additive (atomicAdd combine).
// XCD swizzle: each XCD gets a contiguous unit range -> K/V slice L2-resident.
// R2: loads batched into explicit static arrays (K in 2 halves, V in 2 halves
// issued early, Q per segment) so ~12 loads are in flight per exposure instead
// of load->wait->use chains (VGPR was 56: compiler couldn't batch).  Walk is
// restructured into per-q-tile segments with a branch-free inner j-loop.
// __launch_bounds__(256,4): 4 waves/SIMD, 128-reg budget (8 waves needs <=64
// total incl AGPR -> spills, measured R1: 330 MB scratch traffic).
// ---------------------------------------------------------------------------
__global__ __launch_bounds__(256, 4) void attn_kernel(
    const bf16_t* __restrict__ qh, const bf16_t* __restrict__ ql,
    const bf16_t* __restrict__ kh, const bf16_t* __restrict__ kl,
    const bf16_t* __restrict__ vh,
    float* __restrict__ Oacc, float* __restrict__ lacc)
{
    __shared__ bf16_t Plds[4][2][16 * 72];   // per-wave double-buffered P

    const int tid  = threadIdx.x;
    const int wid  = tid >> 6;
    const int lane = tid & 63;
    const int quad = lane >> 4;
    const int l16  = lane & 15;
    // XCD swizzle: XCD x (bid%8) owns contiguous gw range -> contiguous units
    const int bidx = (blockIdx.x & 7) * 256 + (blockIdx.x >> 3);
    const int gw   = bidx * 4 + wid;                  // 0..8191

    const int U0  = (int)(((long long)gw * UNITS_TOTAL) >> 13);
    const int U1  = (int)(((long long)(gw + 1) * UNITS_TOTAL) >> 13);

    // decode U0 -> (b, a, r, j):  rem = 2a(a+1) + r(a+1) + j
    int b   = U0 / UNITS_PER_B;
    int rem = U0 - b * UNITS_PER_B;
    int a   = (int)((sqrtf((float)(2 * rem) + 1.0f) - 1.0f) * 0.5f);
    while (2 * (a + 1) * (a + 2) <= rem) ++a;
    while (2 * a * (a + 1) > rem) --a;
    int rem2 = rem - 2 * a * (a + 1);
    int r = 0;
    while (rem2 >= (a + 1)) { rem2 -= (a + 1); ++r; }
    int j = rem2;

    int u  = U0;
    int pb = 0;

    while (u < U1) {
        const int m = 4 * a + r;

        // ---- Q for this tile (batched: 4 loads in flight)
        bf16x8 aqh[2], aql[2];
        {
            int qoff = (b * T_ + 16 * m + l16) * H_;
            #pragma unroll
            for (int kk = 0; kk < 2; ++kk) {
                aqh[kk] = *(const bf16x8*)(qh + qoff + kk * 32 + quad * 8);
                aql[kk] = *(const bf16x8*)(ql + qoff + kk * 32 + quad * 8);
            }
        }
        f32x4 O[4];
        float rowsum[4];
        #pragma unroll
        for (int i = 0; i < 4; ++i) { O[i] = (f32x4){0.f,0.f,0.f,0.f}; rowsum[i] = 0.f; }

        // this wave covers j..jend-1 of this q-tile
        int jend = a + 1;
        if (jend - j > U1 - u) jend = j + (U1 - u);
        u += jend - j;

        for (; j < jend; ++j) {
            const int  s0   = 64 * j;
            const bool diag = (j == a);
            const bf16_t* kb = kh + (size_t)(b * T_ + s0) * H_;
            const bf16_t* lb = kl + (size_t)(b * T_ + s0) * H_;
            const bf16_t* vb = vh + (size_t)b * H_ * T_ + s0;

            // ---- K half 1 (nt=0,1): 8 loads batched into regs
            bf16x8 kr[2][2], lr[2][2];
            #pragma unroll
            for (int nt = 0; nt < 2; ++nt)
                #pragma unroll
                for (int kk = 0; kk < 2; ++kk) {
                    int ro = (nt * 16 + l16) * H_ + kk * 32 + quad * 8;
                    kr[nt][kk] = *(const bf16x8*)(kb + ro);
                    lr[nt][kk] = *(const bf16x8*)(lb + ro);
                }
            // ---- V half 1 (ht=0,1): issued early, consumed only at PV
            bf16x8 vr[4][2];
            #pragma unroll
            for (int ht = 0; ht < 2; ++ht)
                #pragma unroll
                for (int kk = 0; kk < 2; ++kk)
                    vr[ht][kk] = *(const bf16x8*)(vb + (ht * 16 + l16) * T_ + kk * 32 + quad * 8);

            // ---- S half 1
            f32x4 S[4];
            #pragma unroll
            for (int i = 0; i < 4; ++i) S[i] = (f32x4){0.f,0.f,0.f,0.f};
            #pragma unroll
            for (int nt = 0; nt < 2; ++nt)
                #pragma unroll
                for (int kk = 0; kk < 2; ++kk) {
                    S[nt] = MFMA16(aqh[kk], kr[nt][kk], S[nt]);
                    S[nt] = MFMA16(aqh[kk], lr[nt][kk], S[nt]);
                    S[nt] = MFMA16(aql[kk], kr[nt][kk], S[nt]);
                }

            // ---- K half 2 (nt=2,3) into the same arrays (WAR after MFMAs)
            #pragma unroll
            for (int nt = 0; nt < 2; ++nt)
                #pragma unroll
                for (int kk = 0; kk < 2; ++kk) {
                    int ro = ((nt + 2) * 16 + l16) * H_ + kk * 32 + quad * 8;
                    kr[nt][kk] = *(const bf16x8*)(kb + ro);
                    lr[nt][kk] = *(const bf16x8*)(lb + ro);
                }
            // ---- V half 2 (ht=2,3)
            #pragma unroll
            for (int ht = 2; ht < 4; ++ht)
                #pragma unroll
                for (int kk = 0; kk < 2; ++kk)
                    vr[ht][kk] = *(const bf16x8*)(vb + (ht * 16 + l16) * T_ + kk * 32 + quad * 8);

            // ---- S half 2
            #pragma unroll
            for (int nt = 0; nt < 2; ++nt)
                #pragma unroll
                for (int kk = 0; kk < 2; ++kk) {
                    S[nt + 2] = MFMA16(aqh[kk], kr[nt][kk], S[nt + 2]);
                    S[nt + 2] = MFMA16(aqh[kk], lr[nt][kk], S[nt + 2]);
                    S[nt + 2] = MFMA16(aql[kk], kr[nt][kk], S[nt + 2]);
                }

            // ---- fixed-max softmax: p = exp(s/8 - 20); no reductions
            bf16_t* Pw = Plds[wid][pb];
            const int rowb = 16 * m + quad * 4;
            #pragma unroll
            for (int nt = 0; nt < 4; ++nt) {
                int colt = s0 + nt * 16 + l16;
                #pragma unroll
                for (int rr = 0; rr < 4; ++rr) {
                    float p = __expf(fmaf(S[nt][rr], 0.125f, -20.0f));
                    if (diag && colt > rowb + rr) p = 0.f;
                    rowsum[rr] += p;
                    Pw[(quad * 4 + rr) * 72 + nt * 16 + l16] = (bf16_t)p;
                }
            }
            pb ^= 1;

            // ---- P: LDS round-trip D-layout -> A-layout (same wave)
            bf16x8 ap[2];
            #pragma unroll
            for (int kk = 0; kk < 2; ++kk)
                ap[kk] = *(const bf16x8*)(Pw + l16 * 72 + kk * 32 + quad * 8);

            // ---- O += P * Vh (V already in regs)
            #pragma unroll
            for (int ht = 0; ht < 4; ++ht) {
                O[ht] = MFMA16(ap[0], vr[ht][0], O[ht]);
                O[ht] = MFMA16(ap[1], vr[ht][1], O[ht]);
            }
        }

        // ---- flush partial results for this q-tile segment
        #pragma unroll
        for (int rr = 0; rr < 4; ++rr) {
            int trow = b * T_ + 16 * m + quad * 4 + rr;
            #pragma unroll
            for (int ht = 0; ht < 4; ++ht)
                atomicAdd(Oacc + trow * H_ + ht * 16 + l16, O[ht][rr]);
            float s_ = rowsum[rr];
            s_ += __shfl_xor(s_, 1, 64);
            s_ += __shfl_xor(s_, 2, 64);
            s_ += __shfl_xor(s_, 4, 64);
            s_ += __shfl_xor(s_, 8, 64);
            if (l16 == 0) atomicAdd(lacc + trow, s_);
        }

        // ---- advance to next q-tile
        j = 0;
        ++r;
        if (r == 4) { r = 0; ++a; if (a == 32) { a = 0; ++b; } }
    }
}

// ---------------------------------------------------------------------------
// Kernel 5: out = Oacc / lacc
// ---------------------------------------------------------------------------
__global__ __launch_bounds__(256) void div_kernel(
    const float* __restrict__ Oacc, const float* __restrict__ lacc,
    float* __restrict__ out)
{
    int i = blockIdx.x * 256 + threadIdx.x;          // f32x4 index, 262144 total
    f32x4 o   = ((const f32x4*)Oacc)[i];
    float inv = 1.0f / lacc[i >> 4];
    ((f32x4*)out)[i] = o * inv;
}

// ---------------------------------------------------------------------------
extern "C" void kernel_launch(void* const* d_in, const int* in_sizes, int n_in,
                              void* d_out, int out_size, void* d_ws, size_t ws_size,
                              hipStream_t stream)
{
    const float* x  = (const float*)d_in[0];
    const float* Wk = (const float*)d_in[1];
    const float* Wq = (const float*)d_in[2];
    const float* Wv = (const float*)d_in[3];
    float* out = (float*)d_out;

    char* ws = (char*)d_ws;
    const size_t WSZ = 192 * 1024 * sizeof(bf16_t);            // 393216
    const size_t QSZ = (size_t)B_ * T_ * H_ * sizeof(bf16_t);  // 2097152
    bf16_t* Wh   = (bf16_t*)(ws);
    bf16_t* Wl   = (bf16_t*)(ws + WSZ);
    bf16_t* qh   = (bf16_t*)(ws + 2 * WSZ);
    bf16_t* ql   = (bf16_t*)(ws + 2 * WSZ + 1 * QSZ);
    bf16_t* kh   = (bf16_t*)(ws + 2 * WSZ + 2 * QSZ);
    bf16_t* kl   = (bf16_t*)(ws + 2 * WSZ + 3 * QSZ);
    bf16_t* vh   = (bf16_t*)(ws + 2 * WSZ + 4 * QSZ);
    float*  Oacc = (float*)(ws + 2 * WSZ + 5 * QSZ);           // 4 MB
    float*  lacc = (float*)(ws + 2 * WSZ + 5 * QSZ + (size_t)B_ * T_ * H_ * 4);

    hipLaunchKernelGGL(zero_kernel, dim3(1040), dim3(256), 0, stream, (f32x4*)Oacc);
    hipLaunchKernelGGL(wconv_kernel, dim3(768), dim3(256), 0, stream, Wk, Wq, Wv, Wh, Wl);
    hipLaunchKernelGGL(proj_kernel, dim3(512), dim3(256), 0, stream,
                       x, Wh, Wl, qh, ql, kh, kl, vh);
    hipLaunchKernelGGL(attn_kernel, dim3(2048), dim3(256), 0, stream,
                       qh, ql, kh, kl, vh, Oacc, lacc);
    hipLaunchKernelGGL(div_kernel, dim3(1024), dim3(256), 0, stream, Oacc, lacc, out);
}

// Round 3
// 200.906 us; speedup vs baseline: 1.3429x; 1.0597x over previous
//
#include <hip/hip_runtime.h>
#include <hip/hip_bf16.h>

typedef __bf16 bf16_t;
typedef __bf16 bf16x8 __attribute__((ext_vector_type(8)));
typedef float  f32x4  __attribute__((ext_vector_type(4)));

#define B_ 8
#define T_ 2048
#define C_ 1024
#define H_ 64

#define MFMA16(a, b, c) __builtin_amdgcn_mfma_f32_16x16x32_bf16((a), (b), (c), 0, 0, 0)

// ---------------------------------------------------------------------------
// Kernel 1: W fp32 -> concatenated hi/lo bf16 [192][1024] (q|k|v rows).
// ---------------------------------------------------------------------------
__global__ __launch_bounds__(256) void wconv_kernel(
    const float* __restrict__ Wk, const float* __restrict__ Wq,
    const float* __restrict__ Wv,
    bf16_t* __restrict__ Wh, bf16_t* __restrict__ Wl)
{
    int i = blockIdx.x * 256 + threadIdx.x;
    int r = i >> 10;
    int c = i & 1023;
    float v;
    if (r < 64)       v = Wq[r * 1024 + c];
    else if (r < 128) v = Wk[(r - 64) * 1024 + c];
    else              v = Wv[(r - 128) * 1024 + c];
    bf16_t h = (bf16_t)v;
    Wh[i] = h;
    Wl[i] = (bf16_t)(v - (float)h);
}

// ---------------------------------------------------------------------------
// Kernel 2: QKV projection.  512 blocks x 32 rows -> 2 blocks/CU so barrier
// drains in one block overlap with compute in the other.  Each wave: 16 rows
// (mhalf) x 96 cols (nhalf), acc[6].  Double-buffered LDS, 1 barrier/iter.
// ---------------------------------------------------------------------------
__global__ __launch_bounds__(256, 2) void proj_kernel(
    const float*  __restrict__ x,
    const bf16_t* __restrict__ Wh, const bf16_t* __restrict__ Wl,
    bf16_t* __restrict__ qh, bf16_t* __restrict__ ql,
    bf16_t* __restrict__ kh, bf16_t* __restrict__ kl,
    bf16_t* __restrict__ vh)
{
    // [dbuf][hi/lo][192 rows x 40 cols] bf16: 61440 B -> 2 blocks/CU (122 KB)
    __shared__ bf16_t Ws[2][2][192 * 40];

    const int tid   = threadIdx.x;
    const int wid   = tid >> 6;
    const int lane  = tid & 63;
    const int quad  = lane >> 4;
    const int l16   = lane & 15;
    const int mhalf = wid >> 1;            // which 16-row group
    const int nhalf = wid & 1;             // which 96-col group
    const int g     = blockIdx.x * 32 + mhalf * 16 + l16;
    const float* xrow = x + (size_t)g * C_;

    bf16x8 wreg[6];
    auto loadW = [&](int k0) {
        #pragma unroll
        for (int it = 0; it < 6; ++it) {
            int c   = tid + it * 256;
            int mat = (c >= 768);
            int cc  = c - (mat ? 768 : 0);
            int row = cc >> 2, prt = cc & 3;
            wreg[it] = *(const bf16x8*)((mat ? Wl : Wh) + row * 1024 + k0 + prt * 8);
        }
    };
    auto storeW = [&](int buf) {
        #pragma unroll
        for (int it = 0; it < 6; ++it) {
            int c   = tid + it * 256;
            int mat = (c >= 768);
            int cc  = c - (mat ? 768 : 0);
            int row = cc >> 2, prt = cc & 3;
            *(bf16x8*)(&Ws[buf][mat][row * 40 + prt * 8]) = wreg[it];
        }
    };

    f32x4 x0a, x0b, x1a, x1b;
    loadW(0);
    storeW(0);
    x0a = *(const f32x4*)(xrow + quad * 8);
    x0b = *(const f32x4*)(xrow + quad * 8 + 4);
    x1a = *(const f32x4*)(xrow + 32 + quad * 8);
    x1b = *(const f32x4*)(xrow + 32 + quad * 8 + 4);

    f32x4 acc[6];
    for (int i = 0; i < 6; ++i) acc[i] = (f32x4){0.f, 0.f, 0.f, 0.f};
    __syncthreads();

    for (int it = 0; it < 32; ++it) {
        const int buf = it & 1;
        if (it + 1 < 32) loadW((it + 1) * 32);

        float xv[8];
        *(f32x4*)xv       = x0a;
        *(f32x4*)(xv + 4) = x0b;
        bf16x8 ah, al;
        #pragma unroll
        for (int jj = 0; jj < 8; ++jj) {
            bf16_t h = (bf16_t)xv[jj];
            ah[jj] = h;
            al[jj] = (bf16_t)(xv[jj] - (float)h);
        }
        x0a = x1a; x0b = x1b;
        if (it + 2 < 32) {
            x1a = *(const f32x4*)(xrow + (it + 2) * 32 + quad * 8);
            x1b = *(const f32x4*)(xrow + (it + 2) * 32 + quad * 8 + 4);
        }

        #pragma unroll
        for (int nt = 0; nt < 6; ++nt) {
            int nrow = (nhalf * 6 + nt) * 16 + l16;
            bf16x8 bh = *(const bf16x8*)(&Ws[buf][0][nrow * 40 + quad * 8]);
            bf16x8 bl = *(const bf16x8*)(&Ws[buf][1][nrow * 40 + quad * 8]);
            acc[nt] = MFMA16(ah, bh, acc[nt]);
            acc[nt] = MFMA16(ah, bl, acc[nt]);
            acc[nt] = MFMA16(al, bh, acc[nt]);
        }

        if (it + 1 < 32) storeW(buf ^ 1);
        __syncthreads();
    }

    // epilogue: D layout col=lane&15, row=quad*4+reg
    const int rowbase = blockIdx.x * 32 + mhalf * 16 + quad * 4;
    for (int nt = 0; nt < 6; ++nt) {
        int n = (nhalf * 6 + nt) * 16 + l16;
        for (int rr = 0; rr < 4; ++rr) {
            int grow = rowbase + rr;
            int bb = grow >> 11, t = grow & 2047;
            float v  = acc[nt][rr];
            bf16_t h = (bf16_t)v;
            if (n < 64) {
                int off = (bb * T_ + t) * H_ + n;
                qh[off] = h; ql[off] = (bf16_t)(v - (float)h);
            } else if (n < 128) {
                int off = (bb * T_ + t) * H_ + (n - 64);
                kh[off] = h; kl[off] = (bf16_t)(v - (float)h);
            } else {
                vh[(bb * H_ + (n - 128)) * T_ + t] = h;
            }
        }
    }
}

// ---------------------------------------------------------------------------
// Kernel 3: attention, self-contained (R3 rewrite).
// Causal-triangle pair balancing: q-tile m (m/4+1 units) paired with q-tile
// 127-m -> every pair costs exactly 33 units.  One 512-thread block per pair
// (512 blocks = 2/CU, fully co-resident, ONE residency round).  The 8 waves
// split the 33 units; partial O/rowsum combine via LDS atomics (ds_add_f32,
// block-local) -- NO device atomics, no Oacc/lacc, no zero/div kernels; the
// divide is fused and out is written directly.
// XCD swizzle: b = bid%8 -> each XCD keeps one batch's K/V (~1 MB) L2-resident.
// Fixed-max softmax p=exp(s/8-20) keeps partials purely additive.
// ---------------------------------------------------------------------------
__global__ __launch_bounds__(512, 4) void attn_kernel(
    const bf16_t* __restrict__ qh, const bf16_t* __restrict__ ql,
    const bf16_t* __restrict__ kh, const bf16_t* __restrict__ kl,
    const bf16_t* __restrict__ vh,
    float* __restrict__ out)
{
    __shared__ bf16_t Plds[8][2][16 * 72];   // per-wave double-buffered P (36 KB)
    __shared__ float  Olds[2][16][64];       // per-tile O accumulators (8 KB)
    __shared__ float  Rs[2][16];             // per-tile rowsum accumulators

    const int tid  = threadIdx.x;
    const int wid  = tid >> 6;
    const int lane = tid & 63;
    const int quad = lane >> 4;
    const int l16  = lane & 15;

    const int b = blockIdx.x & 7;            // XCD-contiguous batch
    const int p = blockIdx.x >> 3;           // pair index 0..63
    const int mT[2] = { p, 127 - p };
    const int cT[2] = { p / 4 + 1, (127 - p) / 4 + 1 };   // units per tile (sum 33)
    const int cA = cT[0];

    // zero LDS accumulators
    {
        float* z = &Olds[0][0][0];
        for (int i = tid; i < 2 * 16 * 64; i += 512) z[i] = 0.f;
        if (tid < 32) Rs[tid >> 4][tid & 15] = 0.f;
    }
    __syncthreads();

    int u    = (wid * 33) >> 3;              // this wave: units [u, uend)
    int uend = ((wid + 1) * 33) >> 3;
    int pb   = 0;

    while (u < uend) {
        const int slot = (u >= cA) ? 1 : 0;
        const int jof  = slot ? cA : 0;
        const int m    = mT[slot];
        const int jdia = cT[slot] - 1;       // diagonal unit index of this tile
        int       j    = u - jof;
        int       jend = slot ? (uend - cA) : (uend < cA ? uend : cA);
        u = jend + jof;

        // ---- Q for this tile (batched: 4 loads in flight)
        bf16x8 aqh[2], aql[2];
        {
            int qoff = (b * T_ + 16 * m + l16) * H_;
            #pragma unroll
            for (int kk = 0; kk < 2; ++kk) {
                aqh[kk] = *(const bf16x8*)(qh + qoff + kk * 32 + quad * 8);
                aql[kk] = *(const bf16x8*)(ql + qoff + kk * 32 + quad * 8);
            }
        }
        f32x4 O[4];
        float rowsum[4];
        #pragma unroll
        for (int i = 0; i < 4; ++i) { O[i] = (f32x4){0.f,0.f,0.f,0.f}; rowsum[i] = 0.f; }

        for (; j < jend; ++j) {
            const int  s0   = 64 * j;
            const bool diag = (j == jdia);
            const bf16_t* kb = kh + (size_t)(b * T_ + s0) * H_;
            const bf16_t* lb = kl + (size_t)(b * T_ + s0) * H_;
            const bf16_t* vb = vh + (size_t)b * H_ * T_ + s0;

            // ---- K half 1 (nt=0,1): 8 loads batched into regs
            bf16x8 kr[2][2], lr[2][2];
            #pragma unroll
            for (int nt = 0; nt < 2; ++nt)
                #pragma unroll
                for (int kk = 0; kk < 2; ++kk) {
                    int ro = (nt * 16 + l16) * H_ + kk * 32 + quad * 8;
                    kr[nt][kk] = *(const bf16x8*)(kb + ro);
                    lr[nt][kk] = *(const bf16x8*)(lb + ro);
                }
            // ---- V half 1 (ht=0,1): issued early, consumed only at PV
            bf16x8 vr[4][2];
            #pragma unroll
            for (int ht = 0; ht < 2; ++ht)
                #pragma unroll
                for (int kk = 0; kk < 2; ++kk)
                    vr[ht][kk] = *(const bf16x8*)(vb + (ht * 16 + l16) * T_ + kk * 32 + quad * 8);

            // ---- S half 1
            f32x4 S[4];
            #pragma unroll
            for (int i = 0; i < 4; ++i) S[i] = (f32x4){0.f,0.f,0.f,0.f};
            #pragma unroll
            for (int nt = 0; nt < 2; ++nt)
                #pragma unroll
                for (int kk = 0; kk < 2; ++kk) {
                    S[nt] = MFMA16(aqh[kk], kr[nt][kk], S[nt]);
                    S[nt] = MFMA16(aqh[kk], lr[nt][kk], S[nt]);
                    S[nt] = MFMA16(aql[kk], kr[nt][kk], S[nt]);
                }

            // ---- K half 2 (nt=2,3) into the same arrays (WAR after MFMAs)
            #pragma unroll
            for (int nt = 0; nt < 2; ++nt)
                #pragma unroll
                for (int kk = 0; kk < 2; ++kk) {
                    int ro = ((nt + 2) * 16 + l16) * H_ + kk * 32 + quad * 8;
                    kr[nt][kk] = *(const bf16x8*)(kb + ro);
                    lr[nt][kk] = *(const bf16x8*)(lb + ro);
                }
            // ---- V half 2 (ht=2,3)
            #pragma unroll
            for (int ht = 2; ht < 4; ++ht)
                #pragma unroll
                for (int kk = 0; kk < 2; ++kk)
                    vr[ht][kk] = *(const bf16x8*)(vb + (ht * 16 + l16) * T_ + kk * 32 + quad * 8);

            // ---- S half 2
            #pragma unroll
            for (int nt = 0; nt < 2; ++nt)
                #pragma unroll
                for (int kk = 0; kk < 2; ++kk) {
                    S[nt + 2] = MFMA16(aqh[kk], kr[nt][kk], S[nt + 2]);
                    S[nt + 2] = MFMA16(aqh[kk], lr[nt][kk], S[nt + 2]);
                    S[nt + 2] = MFMA16(aql[kk], kr[nt][kk], S[nt + 2]);
                }

            // ---- fixed-max softmax: p = exp(s/8 - 20); no reductions
            bf16_t* Pw = Plds[wid][pb];
            const int rowb = 16 * m + quad * 4;
            #pragma unroll
            for (int nt = 0; nt < 4; ++nt) {
                int colt = s0 + nt * 16 + l16;
                #pragma unroll
                for (int rr = 0; rr < 4; ++rr) {
                    float pv = __expf(fmaf(S[nt][rr], 0.125f, -20.0f));
                    if (diag && colt > rowb + rr) pv = 0.f;
                    rowsum[rr] += pv;
                    Pw[(quad * 4 + rr) * 72 + nt * 16 + l16] = (bf16_t)pv;
                }
            }
            pb ^= 1;

            // ---- P: LDS round-trip D-layout -> A-layout (same wave)
            bf16x8 ap[2];
            #pragma unroll
            for (int kk = 0; kk < 2; ++kk)
                ap[kk] = *(const bf16x8*)(Pw + l16 * 72 + kk * 32 + quad * 8);

            // ---- O += P * Vh (V already in regs)
            #pragma unroll
            for (int ht = 0; ht < 4; ++ht) {
                O[ht] = MFMA16(ap[0], vr[ht][0], O[ht]);
                O[ht] = MFMA16(ap[1], vr[ht][1], O[ht]);
            }
        }

        // ---- combine partials block-locally (LDS atomics, no device atomics)
        #pragma unroll
        for (int rr = 0; rr < 4; ++rr) {
            int row = quad * 4 + rr;
            #pragma unroll
            for (int ht = 0; ht < 4; ++ht)
                atomicAdd(&Olds[slot][row][ht * 16 + l16], O[ht][rr]);
            float s_ = rowsum[rr];
            s_ += __shfl_xor(s_, 1, 64);
            s_ += __shfl_xor(s_, 2, 64);
            s_ += __shfl_xor(s_, 4, 64);
            s_ += __shfl_xor(s_, 8, 64);
            if (l16 == 0) atomicAdd(&Rs[slot][row], s_);
        }
    }

    __syncthreads();

    // ---- finalize: 2 tiles x 16 rows x 64 cols; fused divide, direct write
    {
        int idx  = tid * 4;            // 0..2044
        int row  = idx >> 6;           // 0..31
        int col  = idx & 63;
        int slot = row >> 4;
        int r16  = row & 15;
        float inv = 1.0f / Rs[slot][r16];
        f32x4 o = *(const f32x4*)&Olds[slot][r16][col];
        int t = 16 * mT[slot] + r16;
        *(f32x4*)&out[((size_t)(b * T_ + t)) * H_ + col] = o * inv;
    }
}

// ---------------------------------------------------------------------------
extern "C" void kernel_launch(void* const* d_in, const int* in_sizes, int n_in,
                              void* d_out, int out_size, void* d_ws, size_t ws_size,
                              hipStream_t stream)
{
    const float* x  = (const float*)d_in[0];
    const float* Wk = (const float*)d_in[1];
    const float* Wq = (const float*)d_in[2];
    const float* Wv = (const float*)d_in[3];
    float* out = (float*)d_out;

    char* ws = (char*)d_ws;
    const size_t WSZ = 192 * 1024 * sizeof(bf16_t);            // 393216
    const size_t QSZ = (size_t)B_ * T_ * H_ * sizeof(bf16_t);  // 2097152
    bf16_t* Wh   = (bf16_t*)(ws);
    bf16_t* Wl   = (bf16_t*)(ws + WSZ);
    bf16_t* qh   = (bf16_t*)(ws + 2 * WSZ);
    bf16_t* ql   = (bf16_t*)(ws + 2 * WSZ + 1 * QSZ);
    bf16_t* kh   = (bf16_t*)(ws + 2 * WSZ + 2 * QSZ);
    bf16_t* kl   = (bf16_t*)(ws + 2 * WSZ + 3 * QSZ);
    bf16_t* vh   = (bf16_t*)(ws + 2 * WSZ + 4 * QSZ);

    hipLaunchKernelGGL(wconv_kernel, dim3(768), dim3(256), 0, stream, Wk, Wq, Wv, Wh, Wl);
    hipLaunchKernelGGL(proj_kernel, dim3(512), dim3(256), 0, stream,
                       x, Wh, Wl, qh, ql, kh, kl, vh);
    hipLaunchKernelGGL(attn_kernel, dim3(512), dim3(512), 0, stream,
                       qh, ql, kh, kl, vh, out);
}

// Round 4
// 173.803 us; speedup vs baseline: 1.5523x; 1.1559x over previous
//
#include <hip/hip_runtime.h>
#include <hip/hip_bf16.h>

typedef __bf16 bf16_t;
typedef __bf16 bf16x8 __attribute__((ext_vector_type(8)));
typedef float  f32x4  __attribute__((ext_vector_type(4)));

#define B_ 8
#define T_ 2048
#define C_ 1024
#define H_ 64

#define MFMA16(a, b, c) __builtin_amdgcn_mfma_f32_16x16x32_bf16((a), (b), (c), 0, 0, 0)
// async global->LDS, 16B per lane; dest = wave-uniform base + lane*16 (linear)
#define GLL16(g, l) __builtin_amdgcn_global_load_lds( \
    (const __attribute__((address_space(1))) unsigned int*)(g), \
    (__attribute__((address_space(3))) unsigned int*)(l), 16, 0, 0)

// ---------------------------------------------------------------------------
// Kernel 1: W fp32 -> concatenated hi/lo bf16 [192][1024] (q|k|v rows).
// ---------------------------------------------------------------------------
__global__ __launch_bounds__(256) void wconv_kernel(
    const float* __restrict__ Wk, const float* __restrict__ Wq,
    const float* __restrict__ Wv,
    bf16_t* __restrict__ Wh, bf16_t* __restrict__ Wl)
{
    int i = blockIdx.x * 256 + threadIdx.x;
    int r = i >> 10;
    int c = i & 1023;
    float v;
    if (r < 64)       v = Wq[r * 1024 + c];
    else if (r < 128) v = Wk[(r - 64) * 1024 + c];
    else              v = Wv[(r - 128) * 1024 + c];
    bf16_t h = (bf16_t)v;
    Wh[i] = h;
    Wl[i] = (bf16_t)(v - (float)h);
}

// ---------------------------------------------------------------------------
// Kernel 2: QKV projection (unchanged from R3).
// ---------------------------------------------------------------------------
__global__ __launch_bounds__(256, 2) void proj_kernel(
    const float*  __restrict__ x,
    const bf16_t* __restrict__ Wh, const bf16_t* __restrict__ Wl,
    bf16_t* __restrict__ qh, bf16_t* __restrict__ ql,
    bf16_t* __restrict__ kh, bf16_t* __restrict__ kl,
    bf16_t* __restrict__ vh)
{
    __shared__ bf16_t Ws[2][2][192 * 40];

    const int tid   = threadIdx.x;
    const int wid   = tid >> 6;
    const int lane  = tid & 63;
    const int quad  = lane >> 4;
    const int l16   = lane & 15;
    const int mhalf = wid >> 1;
    const int nhalf = wid & 1;
    const int g     = blockIdx.x * 32 + mhalf * 16 + l16;
    const float* xrow = x + (size_t)g * C_;

    bf16x8 wreg[6];
    auto loadW = [&](int k0) {
        #pragma unroll
        for (int it = 0; it < 6; ++it) {
            int c   = tid + it * 256;
            int mat = (c >= 768);
            int cc  = c - (mat ? 768 : 0);
            int row = cc >> 2, prt = cc & 3;
            wreg[it] = *(const bf16x8*)((mat ? Wl : Wh) + row * 1024 + k0 + prt * 8);
        }
    };
    auto storeW = [&](int buf) {
        #pragma unroll
        for (int it = 0; it < 6; ++it) {
            int c   = tid + it * 256;
            int mat = (c >= 768);
            int cc  = c - (mat ? 768 : 0);
            int row = cc >> 2, prt = cc & 3;
            *(bf16x8*)(&Ws[buf][mat][row * 40 + prt * 8]) = wreg[it];
        }
    };

    f32x4 x0a, x0b, x1a, x1b;
    loadW(0);
    storeW(0);
    x0a = *(const f32x4*)(xrow + quad * 8);
    x0b = *(const f32x4*)(xrow + quad * 8 + 4);
    x1a = *(const f32x4*)(xrow + 32 + quad * 8);
    x1b = *(const f32x4*)(xrow + 32 + quad * 8 + 4);

    f32x4 acc[6];
    for (int i = 0; i < 6; ++i) acc[i] = (f32x4){0.f, 0.f, 0.f, 0.f};
    __syncthreads();

    for (int it = 0; it < 32; ++it) {
        const int buf = it & 1;
        if (it + 1 < 32) loadW((it + 1) * 32);

        float xv[8];
        *(f32x4*)xv       = x0a;
        *(f32x4*)(xv + 4) = x0b;
        bf16x8 ah, al;
        #pragma unroll
        for (int jj = 0; jj < 8; ++jj) {
            bf16_t h = (bf16_t)xv[jj];
            ah[jj] = h;
            al[jj] = (bf16_t)(xv[jj] - (float)h);
        }
        x0a = x1a; x0b = x1b;
        if (it + 2 < 32) {
            x1a = *(const f32x4*)(xrow + (it + 2) * 32 + quad * 8);
            x1b = *(const f32x4*)(xrow + (it + 2) * 32 + quad * 8 + 4);
        }

        #pragma unroll
        for (int nt = 0; nt < 6; ++nt) {
            int nrow = (nhalf * 6 + nt) * 16 + l16;
            bf16x8 bh = *(const bf16x8*)(&Ws[buf][0][nrow * 40 + quad * 8]);
            bf16x8 bl = *(const bf16x8*)(&Ws[buf][1][nrow * 40 + quad * 8]);
            acc[nt] = MFMA16(ah, bh, acc[nt]);
            acc[nt] = MFMA16(ah, bl, acc[nt]);
            acc[nt] = MFMA16(al, bh, acc[nt]);
        }

        if (it + 1 < 32) storeW(buf ^ 1);
        __syncthreads();
    }

    const int rowbase = blockIdx.x * 32 + mhalf * 16 + quad * 4;
    for (int nt = 0; nt < 6; ++nt) {
        int n = (nhalf * 6 + nt) * 16 + l16;
        for (int rr = 0; rr < 4; ++rr) {
            int grow = rowbase + rr;
            int bb = grow >> 11, t = grow & 2047;
            float v  = acc[nt][rr];
            bf16_t h = (bf16_t)v;
            if (n < 64) {
                int off = (bb * T_ + t) * H_ + n;
                qh[off] = h; ql[off] = (bf16_t)(v - (float)h);
            } else if (n < 128) {
                int off = (bb * T_ + t) * H_ + (n - 64);
                kh[off] = h; kl[off] = (bf16_t)(v - (float)h);
            } else {
                vh[(bb * H_ + (n - 128)) * T_ + t] = h;
            }
        }
    }
}

// ---------------------------------------------------------------------------
// Kernel 3: attention (R4 rewrite: block-cooperative LDS staging).
// 512 blocks x 512 threads (8 waves, 2 blocks/CU).  Block = (b, q-block pair
// g/15-g of 128 rows, j-slice s of 8).  Pair work = 34 j-steps; slice s takes
// u = s, s+8, ... (4-5 steps).  Per j-step the block stages Kh/Kl/V 64-key
// tiles (24 KB) ONCE via global_load_lds (no dest VGPRs -> load latency is off
// the register allocator's hands), double-buffered, counted vmcnt(3) so next
// tiles stream under current compute.  Wave w owns q-rows 128g+16w..+15; each
// wave's ds_read fragments are LINEAR (addr = lane*16B): conflict-free.
// Combine across j-slices: Oacc/lacc global atomics (zeroed by memsetAsync).
// Fixed-max softmax p=exp(s/8-20); mask applied unconditionally (colt>rowt).
// ---------------------------------------------------------------------------
__global__ __launch_bounds__(512, 4) void attn_kernel(
    const bf16_t* __restrict__ qh, const bf16_t* __restrict__ ql,
    const bf16_t* __restrict__ kh, const bf16_t* __restrict__ kl,
    const bf16_t* __restrict__ vh,
    float* __restrict__ Oacc, float* __restrict__ lacc)
{
    __shared__ bf16_t KV[2][3][4096];     // [dbuf][kh|kl|v][64x64] = 48 KB
    __shared__ bf16_t Plds[8][16 * 72];   // per-wave P buffer, 18 KB

    const int tid  = threadIdx.x;
    const int wid  = tid >> 6;
    const int lane = tid & 63;
    const int quad = lane >> 4;
    const int l16  = lane & 15;

    const int b  = blockIdx.x & 7;         // XCD-aligned batch
    const int gp = (blockIdx.x >> 3) & 7;  // pair index
    const int s  = blockIdx.x >> 6;        // j-slice 0..7
    const int gA = gp, gB = 15 - gp;
    const int nA = 2 * gA + 2;             // j-steps of tile A (tile B: 34-nA)

    // staging source mapping: thread tid fills LDS slot tid (16B), slot order
    // chosen so reader's ds_read addr = group*1024 + lane*16 (linear).
    const int t_nt   = wid >> 1;
    const int t_kk   = wid & 1;
    const int t_l16  = tid & 15;
    const int t_quad = (tid >> 4) & 3;
    const int koff   = (t_nt * 16 + t_l16) * H_ + t_kk * 32 + t_quad * 8;
    const int voff   = (t_nt * 16 + t_l16) * T_ + t_kk * 32 + t_quad * 8;

    auto stage = [&](int j, int bufi) {
        const size_t kbase = (size_t)(b * T_ + 64 * j) * H_;
        GLL16(kh + kbase + koff, &KV[bufi][0][wid * 512]);
        GLL16(kl + kbase + koff, &KV[bufi][1][wid * 512]);
        GLL16(vh + (size_t)b * H_ * T_ + 64 * j + voff, &KV[bufi][2][wid * 512]);
    };

    f32x4  O[4];
    float  rowsum[4];
    bf16x8 aqh[2], aql[2];
    int    gcur = -1;

    auto flushO = [&]() {
        #pragma unroll
        for (int rr = 0; rr < 4; ++rr) {
            int trow = b * T_ + 128 * gcur + 16 * wid + quad * 4 + rr;
            #pragma unroll
            for (int ht = 0; ht < 4; ++ht)
                atomicAdd(Oacc + (size_t)trow * H_ + ht * 16 + l16, O[ht][rr]);
            float s_ = rowsum[rr];
            s_ += __shfl_xor(s_, 1, 64);
            s_ += __shfl_xor(s_, 2, 64);
            s_ += __shfl_xor(s_, 4, 64);
            s_ += __shfl_xor(s_, 8, 64);
            if (l16 == 0) atomicAdd(lacc + trow, s_);
        }
    };

    // prologue: stage first unit
    {
        int u0 = s;
        int j0 = (u0 < nA) ? u0 : (u0 - nA);
        stage(j0, 0);
    }

    int buf = 0;
    for (int u = s; u < 34; u += 8) {
        const int g = (u < nA) ? gA : gB;
        const int j = (u < nA) ? u : (u - nA);

        const int un = u + 8;
        if (un < 34) {
            int jn = (un < nA) ? un : (un - nA);
            stage(jn, buf ^ 1);
            asm volatile("s_waitcnt vmcnt(3)" ::: "memory");  // cur tiles done
        } else {
            asm volatile("s_waitcnt vmcnt(0)" ::: "memory");
        }
        __syncthreads();   // all waves' slices of cur buffer complete

        // ---- tile change: flush previous partials, load Q for new tile
        if (g != gcur) {
            if (gcur >= 0) flushO();
            gcur = g;
            const size_t qoff = (size_t)(b * T_ + 128 * g + 16 * wid + l16) * H_;
            #pragma unroll
            for (int kk = 0; kk < 2; ++kk) {
                aqh[kk] = *(const bf16x8*)(qh + qoff + kk * 32 + quad * 8);
                aql[kk] = *(const bf16x8*)(ql + qoff + kk * 32 + quad * 8);
            }
            #pragma unroll
            for (int i = 0; i < 4; ++i) { O[i] = (f32x4){0.f,0.f,0.f,0.f}; rowsum[i] = 0.f; }
        }

        // ---- S = q k^T (3-term hi/lo), K fragments linear from LDS
        const bf16_t* Kh = KV[buf][0];
        const bf16_t* Kl = KV[buf][1];
        f32x4 S[4];
        #pragma unroll
        for (int i = 0; i < 4; ++i) S[i] = (f32x4){0.f,0.f,0.f,0.f};
        #pragma unroll
        for (int nt = 0; nt < 4; ++nt) {
            #pragma unroll
            for (int kk = 0; kk < 2; ++kk) {
                bf16x8 bh = *(const bf16x8*)(Kh + (nt * 2 + kk) * 512 + lane * 8);
                bf16x8 bl = *(const bf16x8*)(Kl + (nt * 2 + kk) * 512 + lane * 8);
                S[nt] = MFMA16(aqh[kk], bh, S[nt]);
                S[nt] = MFMA16(aqh[kk], bl, S[nt]);
                S[nt] = MFMA16(aql[kk], bh, S[nt]);
            }
        }

        // ---- fixed-max softmax: p = exp(s/8 - 20); unconditional causal mask
        bf16_t* Pw = Plds[wid];
        const int rloc = 128 * g + 16 * wid + quad * 4;
        #pragma unroll
        for (int nt = 0; nt < 4; ++nt) {
            int colt = 64 * j + nt * 16 + l16;
            #pragma unroll
            for (int rr = 0; rr < 4; ++rr) {
                float pv = (colt <= rloc + rr)
                         ? __expf(fmaf(S[nt][rr], 0.125f, -20.0f)) : 0.f;
                rowsum[rr] += pv;
                Pw[(quad * 4 + rr) * 72 + nt * 16 + l16] = (bf16_t)pv;
            }
        }

        // ---- P: LDS round-trip D-layout -> A-layout (same wave, HW-ordered)
        bf16x8 ap0 = *(const bf16x8*)(Pw + l16 * 72 + quad * 8);
        bf16x8 ap1 = *(const bf16x8*)(Pw + l16 * 72 + 32 + quad * 8);

        // ---- O += P * V, V fragments linear from LDS
        const bf16_t* Vt = KV[buf][2];
        #pragma unroll
        for (int ht = 0; ht < 4; ++ht) {
            bf16x8 bv0 = *(const bf16x8*)(Vt + (ht * 2 + 0) * 512 + lane * 8);
            bf16x8 bv1 = *(const bf16x8*)(Vt + (ht * 2 + 1) * 512 + lane * 8);
            O[ht] = MFMA16(ap0, bv0, O[ht]);
            O[ht] = MFMA16(ap1, bv1, O[ht]);
        }

        __syncthreads();   // done reading cur buffer before it is re-staged
        buf ^= 1;
    }
    if (gcur >= 0) flushO();
}

// ---------------------------------------------------------------------------
// Kernel 4: out = Oacc / lacc
// ---------------------------------------------------------------------------
__global__ __launch_bounds__(256) void div_kernel(
    const float* __restrict__ Oacc, const float* __restrict__ lacc,
    float* __restrict__ out)
{
    int i = blockIdx.x * 256 + threadIdx.x;          // f32x4 index, 262144 total
    f32x4 o   = ((const f32x4*)Oacc)[i];
    float inv = 1.0f / lacc[i >> 4];
    ((f32x4*)out)[i] = o * inv;
}

// ---------------------------------------------------------------------------
extern "C" void kernel_launch(void* const* d_in, const int* in_sizes, int n_in,
                              void* d_out, int out_size, void* d_ws, size_t ws_size,
                              hipStream_t stream)
{
    const float* x  = (const float*)d_in[0];
    const float* Wk = (const float*)d_in[1];
    const float* Wq = (const float*)d_in[2];
    const float* Wv = (const float*)d_in[3];
    float* out = (float*)d_out;

    char* ws = (char*)d_ws;
    const size_t WSZ = 192 * 1024 * sizeof(bf16_t);            // 393216
    const size_t QSZ = (size_t)B_ * T_ * H_ * sizeof(bf16_t);  // 2097152
    bf16_t* Wh   = (bf16_t*)(ws);
    bf16_t* Wl   = (bf16_t*)(ws + WSZ);
    bf16_t* qh   = (bf16_t*)(ws + 2 * WSZ);
    bf16_t* ql   = (bf16_t*)(ws + 2 * WSZ + 1 * QSZ);
    bf16_t* kh   = (bf16_t*)(ws + 2 * WSZ + 2 * QSZ);
    bf16_t* kl   = (bf16_t*)(ws + 2 * WSZ + 3 * QSZ);
    bf16_t* vh   = (bf16_t*)(ws + 2 * WSZ + 4 * QSZ);
    float*  Oacc = (float*)(ws + 2 * WSZ + 5 * QSZ);           // 4 MB
    float*  lacc = (float*)(ws + 2 * WSZ + 5 * QSZ + (size_t)B_ * T_ * H_ * 4);

    // zero Oacc (4 MB) + lacc (64 KB), contiguous
    hipMemsetAsync(Oacc, 0, (size_t)B_ * T_ * H_ * 4 + (size_t)B_ * T_ * 4, stream);
    hipLaunchKernelGGL(wconv_kernel, dim3(768), dim3(256), 0, stream, Wk, Wq, Wv, Wh, Wl);
    hipLaunchKernelGGL(proj_kernel, dim3(512), dim3(256), 0, stream,
                       x, Wh, Wl, qh, ql, kh, kl, vh);
    hipLaunchKernelGGL(attn_kernel, dim3(512), dim3(512), 0, stream,
                       qh, ql, kh, kl, vh, Oacc, lacc);
    hipLaunchKernelGGL(div_kernel, dim3(1024), dim3(256), 0, stream, Oacc, lacc, out);
}